// Round 5
// baseline (534.025 us; speedup 1.0000x reference)
//
#include <hip/hip_runtime.h>
#include <cstdint>
#include <cstddef>

#define DFEAT 512
#define BM 128
#define BN 128
#define BK 32

typedef __attribute__((ext_vector_type(8))) short bf16x8;
typedef __attribute__((ext_vector_type(4))) float f32x4;

#define GLOBAL_AS __attribute__((address_space(1)))
#define LDS_AS __attribute__((address_space(3)))

// float -> bf16 round-to-nearest-even (finite inputs)
__device__ __forceinline__ unsigned short f2bf(float f) {
  unsigned u = __float_as_uint(f);
  u = u + 0x7fffu + ((u >> 16) & 1u);
  return (unsigned short)(u >> 16);
}

__device__ __forceinline__ float bf2f_lo(unsigned u) { return __uint_as_float(u << 16); }
__device__ __forceinline__ float bf2f_hi(unsigned u) { return __uint_as_float(u & 0xffff0000u); }

__device__ __forceinline__ void gl_lds16(const void* g, void* l) {
  __builtin_amdgcn_global_load_lds((const GLOBAL_AS unsigned int*)g,
                                   (LDS_AS unsigned int*)l, 16, 0, 0);
}

// Fused independent preprocessing: deg-count (atomics) || Wt transpose-cast ||
// Xb cast. deg starts at 0 (hipMemsetAsync); true degree = deg+1 (self-loop
// folded arithmetically). Merging converts sum-of-durations into max().
__global__ void k_pre(const int* __restrict__ dst, int* __restrict__ deg, int E,
                      const float* __restrict__ W, unsigned short* __restrict__ Wt,
                      const float* __restrict__ X, unsigned short* __restrict__ Xb,
                      int total8) {
  const int cb = (E + 255) >> 8;
  int b = blockIdx.x;
  if (b < cb) {                      // edge count
    int i = b * 256 + threadIdx.x;
    if (i < E) atomicAdd(&deg[dst[i]], 1);
    return;
  }
  b -= cb;
  if (b < 1024) {                    // Wt[n][k] = bf16(W[k][n]), coalesced read
    int i = b * 256 + threadIdx.x;
    int k = i >> 9, n = i & 511;
    Wt[(size_t)n * DFEAT + k] = f2bf(W[i]);
    return;
  }
  b -= 1024;                         // Xb = bf16(X), 8 elems/thread
  int i = b * 256 + threadIdx.x;
  if (i >= total8) return;
  const float4 a = *reinterpret_cast<const float4*>(X + (size_t)i * 8);
  const float4 c = *reinterpret_cast<const float4*>(X + (size_t)i * 8 + 4);
  uint4 o;
  o.x = (unsigned)f2bf(a.x) | ((unsigned)f2bf(a.y) << 16);
  o.y = (unsigned)f2bf(a.z) | ((unsigned)f2bf(a.w) << 16);
  o.z = (unsigned)f2bf(c.x) | ((unsigned)f2bf(c.y) << 16);
  o.w = (unsigned)f2bf(c.z) | ((unsigned)f2bf(c.w) << 16);
  *reinterpret_cast<uint4*>(Xb + (size_t)i * 8) = o;
}

// single-block exclusive scan of (deg[i]+1) -> rowStart[0..N] and fillPos[0..N).
// R1-style: one 1024-wide Hillis-Steele (20 barriers total), per-thread serial
// chunk of C elements. (R4's tiled version had 312 barriers on one CU — slower.)
__global__ __launch_bounds__(1024) void k_scan(const int* __restrict__ deg,
                                               int* __restrict__ rowStart,
                                               int* __restrict__ fillPos, int N) {
  const int t = threadIdx.x;
  const int C = (N + 1023) / 1024;
  int lo = t * C;
  int hi = lo + C; if (hi > N) hi = N; if (lo > N) lo = N;
  int sum = 0;
  for (int i = lo; i < hi; ++i) sum += deg[i] + 1;
  __shared__ int sm[1024];
  sm[t] = sum;
  __syncthreads();
  for (int d = 1; d < 1024; d <<= 1) {
    int v = (t >= d) ? sm[t - d] : 0;
    __syncthreads();
    sm[t] += v;
    __syncthreads();
  }
  int off = sm[t] - sum;  // exclusive prefix for this chunk
  for (int i = lo; i < hi; ++i) {
    rowStart[i] = off; fillPos[i] = off;
    off += deg[i] + 1;
  }
  if (t == 1023) rowStart[N] = sm[1023];
}

// cw[pos] = { src, rsqrt(deg[src]+1) }; pos straight from the fillPos cursor.
__global__ void k_fill(const int* __restrict__ src, const int* __restrict__ dst,
                       int* __restrict__ fillPos, int2* __restrict__ cw,
                       const int* __restrict__ deg, int E, int N) {
  int i = blockIdx.x * blockDim.x + threadIdx.x;
  if (i >= E + N) return;
  int d, s;
  if (i < E) { d = dst[i]; s = src[i]; }
  else       { d = i - E; s = d; }        // self-loop
  int pos = atomicAdd(&fillPos[d], 1);
  int2 q; q.x = s; q.y = __float_as_int(rsqrtf((float)(deg[s] + 1)));
  cw[pos] = q;
}

// 8-deep gather batch: 8 independent cw loads then 8 independent 1KB row
// gathers in flight per wave. TAIL variant clamps the index to e-1 and zeroes
// the weight — duplicate clamped loads are same-address (L1-hit).
template <bool TAIL>
__device__ __forceinline__ void agg8(const unsigned short* __restrict__ Xb,
                                     const int2* __restrict__ cw,
                                     int p, int e, int lane, float* acc) {
  int2 q[8];
#pragma unroll
  for (int i = 0; i < 8; ++i) {
    int pi = p + i;
    if (TAIL) pi = (pi < e) ? pi : (e - 1);
    q[i] = cw[pi];
  }
  uint4 v[8];
#pragma unroll
  for (int i = 0; i < 8; ++i)
    v[i] = *reinterpret_cast<const uint4*>(Xb + (size_t)q[i].x * DFEAT + lane * 8);
#pragma unroll
  for (int i = 0; i < 8; ++i) {
    float w = __int_as_float(q[i].y);
    if (TAIL) w = (p + i < e) ? w : 0.0f;
    acc[0] = fmaf(w, bf2f_lo(v[i].x), acc[0]); acc[1] = fmaf(w, bf2f_hi(v[i].x), acc[1]);
    acc[2] = fmaf(w, bf2f_lo(v[i].y), acc[2]); acc[3] = fmaf(w, bf2f_hi(v[i].y), acc[3]);
    acc[4] = fmaf(w, bf2f_lo(v[i].z), acc[4]); acc[5] = fmaf(w, bf2f_hi(v[i].z), acc[5]);
    acc[6] = fmaf(w, bf2f_lo(v[i].w), acc[6]); acc[7] = fmaf(w, bf2f_hi(v[i].w), acc[7]);
  }
}

// One wave per dst row; lane handles features [lane*8, lane*8+8).
// Launched in 4 quarters (~32 µs each): pushes agg below the mid-tier kernels
// so the global top-5 window exposes them. Row scale = rsqrt(e-s) (== deg+1).
__global__ __launch_bounds__(256) void k_aggregate(const unsigned short* __restrict__ Xb,
                                                   const int2* __restrict__ cw,
                                                   const int* __restrict__ rowStart,
                                                   unsigned short* __restrict__ Y,
                                                   int N, int rowOff) {
  const int row = rowOff + blockIdx.x * 4 + (threadIdx.x >> 6);
  const int lane = threadIdx.x & 63;
  float acc[8] = {0.f, 0.f, 0.f, 0.f, 0.f, 0.f, 0.f, 0.f};
  if (row < N) {
    const int s = rowStart[row], e = rowStart[row + 1];  // e > s always (self-loop)
    int p = s;
    for (; p + 8 <= e; p += 8) agg8<false>(Xb, cw, p, e, lane, acc);
    if (p < e) agg8<true>(Xb, cw, p, e, lane, acc);
    const float sc = rsqrtf((float)(e - s));
#pragma unroll
    for (int j = 0; j < 8; ++j) acc[j] *= sc;
  }
  uint4 o;
  o.x = (unsigned)f2bf(acc[0]) | ((unsigned)f2bf(acc[1]) << 16);
  o.y = (unsigned)f2bf(acc[2]) | ((unsigned)f2bf(acc[3]) << 16);
  o.z = (unsigned)f2bf(acc[4]) | ((unsigned)f2bf(acc[5]) << 16);
  o.w = (unsigned)f2bf(acc[6]) | ((unsigned)f2bf(acc[7]) << 16);
  *reinterpret_cast<uint4*>(Y + (size_t)row * DFEAT + lane * 8) = o;
}

// out[M x 512] = LeakyReLU( Y(bf16) @ W + b ). 128x128 tile, BK=32,
// global_load_lds width-16 staging, 4 waves x (64x64 via 4x4 mfma 16x16x32).
// 1D grid, n-fastest + bijective chunked XCD swizzle (m204 form: nwg%8 != 0).
__global__ __launch_bounds__(256) void k_gemm(const unsigned short* __restrict__ Y,
                                              const unsigned short* __restrict__ Wt,
                                              const float* __restrict__ bias,
                                              float* __restrict__ out, int M) {
  __shared__ unsigned short As[BM * BK];  // 8 KB
  __shared__ unsigned short Bs[BN * BK];  // 8 KB
  const int tid = threadIdx.x;
  const int lane = tid & 63;
  const int wave = tid >> 6;
  const int l16 = lane & 15;
  const int quad = lane >> 4;
  const int wm = (wave >> 1) * 64;
  const int wn = (wave & 1) * 64;

  // bijective chunked XCD swizzle (nwg = Mtiles*4 = 1564, q=195, r=4)
  const int nwg = gridDim.x;
  const int q8 = nwg >> 3, r8 = nwg & 7;
  const int xcd = blockIdx.x & 7, loc = blockIdx.x >> 3;
  const int wg = (xcd < r8 ? xcd * (q8 + 1) : r8 * (q8 + 1) + (xcd - r8) * q8) + loc;
  const int m0 = (wg >> 2) * BM;   // n fastest -> A-panel reuse across 4 consecutive wg
  const int n0 = (wg & 3) * BN;

  f32x4 acc[4][4];
#pragma unroll
  for (int mi = 0; mi < 4; ++mi)
#pragma unroll
    for (int ni = 0; ni < 4; ++ni) { f32x4 z = {0.f, 0.f, 0.f, 0.f}; acc[mi][ni] = z; }

  // staging: LDS slot ci (16B units) holds global chunk (row=ci>>2, kq=((ci&3)-(row>>1))&3)
  const int ci0 = wave * 64 + lane;
  const int ci1 = 256 + ci0;
  const int ra0 = ci0 >> 2, ka0 = (((ci0 & 3) - (ra0 >> 1)) & 3) * 8;
  const int ra1 = ci1 >> 2, ka1 = (((ci1 & 3) - (ra1 >> 1)) & 3) * 8;

  const unsigned short* Ag0 = Y + (size_t)(m0 + ra0) * DFEAT + ka0;
  const unsigned short* Ag1 = Y + (size_t)(m0 + ra1) * DFEAT + ka1;
  const unsigned short* Bg0 = Wt + (size_t)(n0 + ra0) * DFEAT + ka0;
  const unsigned short* Bg1 = Wt + (size_t)(n0 + ra1) * DFEAT + ka1;
  unsigned short* La0 = As + ci0 * 8;
  unsigned short* La1 = As + ci1 * 8;
  unsigned short* Lb0 = Bs + ci0 * 8;
  unsigned short* Lb1 = Bs + ci1 * 8;

  // read side: fragment (row, kq=quad) lives at slot row*4 + ((quad + (row>>1)) & 3)
  const int rotA = (quad + ((wm + l16) >> 1)) & 3;   // same for all mi (16*mi/2 % 4 == 0)
  const int rotB = (quad + ((wn + l16) >> 1)) & 3;
  const unsigned short* AsRd = As + (wm + l16) * BK + rotA * 8;
  const unsigned short* BsRd = Bs + (wn + l16) * BK + rotB * 8;

  for (int kk = 0; kk < DFEAT; kk += BK) {
    gl_lds16(Ag0 + kk, La0);
    gl_lds16(Ag1 + kk, La1);
    gl_lds16(Bg0 + kk, Lb0);
    gl_lds16(Bg1 + kk, Lb1);
    __syncthreads();  // drains vmcnt (global_load_lds) per m97 semantics
    bf16x8 av[4], bv[4];
#pragma unroll
    for (int mi = 0; mi < 4; ++mi)
      av[mi] = *reinterpret_cast<const bf16x8*>(AsRd + mi * 16 * BK);
#pragma unroll
    for (int ni = 0; ni < 4; ++ni)
      bv[ni] = *reinterpret_cast<const bf16x8*>(BsRd + ni * 16 * BK);
#pragma unroll
    for (int mi = 0; mi < 4; ++mi)
#pragma unroll
      for (int ni = 0; ni < 4; ++ni)
        acc[mi][ni] = __builtin_amdgcn_mfma_f32_16x16x32_bf16(av[mi], bv[ni], acc[mi][ni], 0, 0, 0);
    __syncthreads();  // protect LDS before next stage
  }

  float bvals[4];
#pragma unroll
  for (int ni = 0; ni < 4; ++ni) bvals[ni] = bias[n0 + wn + 16 * ni + l16];

  // C/D layout: col = lane&15, row = quad*4 + r
#pragma unroll
  for (int mi = 0; mi < 4; ++mi) {
#pragma unroll
    for (int r = 0; r < 4; ++r) {
      int row = m0 + wm + 16 * mi + quad * 4 + r;
      if (row < M) {
#pragma unroll
        for (int ni = 0; ni < 4; ++ni) {
          float v = acc[mi][ni][r] + bvals[ni];
          v = (v >= 0.f) ? v : 0.01f * v;
          out[(size_t)row * DFEAT + n0 + wn + 16 * ni + l16] = v;
        }
      }
    }
  }
}

extern "C" void kernel_launch(void* const* d_in, const int* in_sizes, int n_in,
                              void* d_out, int out_size, void* d_ws, size_t ws_size,
                              hipStream_t stream) {
  const float* X = (const float*)d_in[0];
  const float* W = (const float*)d_in[1];
  const float* b = (const float*)d_in[2];
  const int* ei  = (const int*)d_in[3];
  const int D = DFEAT;
  const int N = in_sizes[0] / D;   // 50000
  const int E = in_sizes[3] / 2;   // 800000
  const int* src = ei;
  const int* dst = ei + E;
  float* out = (float*)d_out;

  // carve workspace (256B-aligned slices)
  uintptr_t p = (uintptr_t)d_ws;
  auto carve = [&](size_t bytes) -> void* {
    uintptr_t r = p;
    p += (bytes + 255) & ~(size_t)255;
    return (void*)r;
  };
  int*   deg      = (int*)carve(sizeof(int) * (size_t)N);
  int*   rowStart = (int*)carve(sizeof(int) * (size_t)(N + 1));
  int*   fillPos  = (int*)carve(sizeof(int) * (size_t)N);
  int2*  cw       = (int2*)carve(sizeof(int2) * (size_t)(E + N));
  unsigned short* Wt = (unsigned short*)carve(sizeof(unsigned short) * (size_t)D * D);
  const int Mtiles = (N + BM - 1) / BM;     // 391
  const int Mpad = Mtiles * BM;             // 50048
  unsigned short* Y  = (unsigned short*)carve(sizeof(unsigned short) * (size_t)Mpad * D);

  // Xb (bf16 X) lives in d_out: 51.2 MB needed, 102.4 MB available; dead before k_gemm writes.
  unsigned short* Xb = (unsigned short*)d_out;

  const int total8 = N * D / 8;
  const int cb = (E + 255) / 256;
  const int xb = (total8 + 255) / 256;
  const int quarter = ((Mpad / 4 + 3) & ~3);   // 12512, multiple of 4 rows/block

  hipMemsetAsync(deg, 0, sizeof(int) * (size_t)N, stream);
  hipLaunchKernelGGL(k_pre,   dim3(cb + 1024 + xb), dim3(256), 0, stream,
                     dst, deg, E, W, Wt, X, Xb, total8);
  hipLaunchKernelGGL(k_scan,  dim3(1), dim3(1024), 0, stream, deg, rowStart, fillPos, N);
  hipLaunchKernelGGL(k_fill,  dim3((E + N + 255) / 256), dim3(256), 0, stream,
                     src, dst, fillPos, cw, deg, E, N);
  for (int qq = 0; qq < 4; ++qq) {
    const int ro = qq * quarter;
    const int nr = (qq == 3) ? (Mpad - 3 * quarter) : quarter;
    hipLaunchKernelGGL(k_aggregate, dim3(nr / 4), dim3(256), 0, stream,
                       Xb, cw, rowStart, Y, N, ro);
  }
  hipLaunchKernelGGL(k_gemm,  dim3(Mtiles * 4), dim3(256), 0, stream, Y, Wt, b, out, N);
}

// Round 6
// 445.957 us; speedup vs baseline: 1.1975x; 1.1975x over previous
//
#include <hip/hip_runtime.h>
#include <cstdint>
#include <cstddef>

#define DFEAT 512
#define BM 128
#define BN 128
#define BK 32

typedef __attribute__((ext_vector_type(8))) short bf16x8;
typedef __attribute__((ext_vector_type(4))) float f32x4;

#define GLOBAL_AS __attribute__((address_space(1)))
#define LDS_AS __attribute__((address_space(3)))

// float -> bf16 round-to-nearest-even (finite inputs)
__device__ __forceinline__ unsigned short f2bf(float f) {
  unsigned u = __float_as_uint(f);
  u = u + 0x7fffu + ((u >> 16) & 1u);
  return (unsigned short)(u >> 16);
}

__device__ __forceinline__ float bf2f_lo(unsigned u) { return __uint_as_float(u << 16); }
__device__ __forceinline__ float bf2f_hi(unsigned u) { return __uint_as_float(u & 0xffff0000u); }

__device__ __forceinline__ void gl_lds16(const void* g, void* l) {
  __builtin_amdgcn_global_load_lds((const GLOBAL_AS unsigned int*)g,
                                   (LDS_AS unsigned int*)l, 16, 0, 0);
}

// Fused independent preprocessing: deg-count (atomics) || Wt transpose-cast ||
// Xb cast. deg starts at 0 (hipMemsetAsync); true degree = deg+1 (self-loop
// folded arithmetically). Merging converts sum-of-durations into max().
__global__ void k_pre(const int* __restrict__ dst, int* __restrict__ deg, int E,
                      const float* __restrict__ W, unsigned short* __restrict__ Wt,
                      const float* __restrict__ X, unsigned short* __restrict__ Xb,
                      int total8) {
  const int cb = (E + 255) >> 8;
  int b = blockIdx.x;
  if (b < cb) {                      // edge count
    int i = b * 256 + threadIdx.x;
    if (i < E) atomicAdd(&deg[dst[i]], 1);
    return;
  }
  b -= cb;
  if (b < 1024) {                    // Wt[n][k] = bf16(W[k][n]), coalesced read
    int i = b * 256 + threadIdx.x;
    int k = i >> 9, n = i & 511;
    Wt[(size_t)n * DFEAT + k] = f2bf(W[i]);
    return;
  }
  b -= 1024;                         // Xb = bf16(X), 8 elems/thread
  int i = b * 256 + threadIdx.x;
  if (i >= total8) return;
  const float4 a = *reinterpret_cast<const float4*>(X + (size_t)i * 8);
  const float4 c = *reinterpret_cast<const float4*>(X + (size_t)i * 8 + 4);
  uint4 o;
  o.x = (unsigned)f2bf(a.x) | ((unsigned)f2bf(a.y) << 16);
  o.y = (unsigned)f2bf(a.z) | ((unsigned)f2bf(a.w) << 16);
  o.z = (unsigned)f2bf(c.x) | ((unsigned)f2bf(c.y) << 16);
  o.w = (unsigned)f2bf(c.z) | ((unsigned)f2bf(c.w) << 16);
  *reinterpret_cast<uint4*>(Xb + (size_t)i * 8) = o;
}

// Multi-block recompute-prefix scan of (deg[i]+1) -> rowStart/fillPos.
// Block b: (1) coalesced sum of deg[0..b*1024) + LDS tree reduce = prefix base
// (redundant ~5 MB total across 49 blocks — latency-hidden, no inter-block
// dep); (2) 1024-wide Hillis-Steele over its own chunk; (3) write out.
// Replaces the single-block scan that ran 109 µs on one CU at 4.6 GB/s.
__global__ __launch_bounds__(1024) void k_scan(const int* __restrict__ deg,
                                               int* __restrict__ rowStart,
                                               int* __restrict__ fillPos, int N) {
  const int t = threadIdx.x;
  const int base = blockIdx.x * 1024;
  __shared__ int sm[1024];
  // 1) prefix base = sum_{i<base} (deg[i]+1)
  int pre = 0;
  for (int i = t; i < base; i += 1024) pre += deg[i] + 1;
  sm[t] = pre;
  __syncthreads();
  for (int d = 512; d > 0; d >>= 1) {
    if (t < d) sm[t] += sm[t + d];
    __syncthreads();
  }
  const int blockBase = sm[0];
  __syncthreads();
  // 2) block-local inclusive scan of v = deg[base+t]+1
  const int idx = base + t;
  int v = (idx < N) ? (deg[idx] + 1) : 0;
  sm[t] = v;
  __syncthreads();
  for (int d = 1; d < 1024; d <<= 1) {
    const int o = (t >= d) ? sm[t - d] : 0;
    __syncthreads();
    sm[t] += o;
    __syncthreads();
  }
  if (idx < N) {
    const int ex = blockBase + sm[t] - v;   // exclusive prefix
    rowStart[idx] = ex;
    fillPos[idx] = ex;
    if (idx == N - 1) rowStart[N] = ex + v;
  }
}

// cw[pos] = { src, rsqrt(deg[src]+1) }; pos straight from the fillPos cursor.
__global__ void k_fill(const int* __restrict__ src, const int* __restrict__ dst,
                       int* __restrict__ fillPos, int2* __restrict__ cw,
                       const int* __restrict__ deg, int E, int N) {
  int i = blockIdx.x * blockDim.x + threadIdx.x;
  if (i >= E + N) return;
  int d, s;
  if (i < E) { d = dst[i]; s = src[i]; }
  else       { d = i - E; s = d; }        // self-loop
  int pos = atomicAdd(&fillPos[d], 1);
  int2 q; q.x = s; q.y = __float_as_int(rsqrtf((float)(deg[s] + 1)));
  cw[pos] = q;
}

// 8-deep gather batch: 8 independent cw loads then 8 independent 1KB row
// gathers in flight per wave. TAIL variant clamps the index to e-1 and zeroes
// the weight — duplicate clamped loads are same-address (L1-hit).
template <bool TAIL>
__device__ __forceinline__ void agg8(const unsigned short* __restrict__ Xb,
                                     const int2* __restrict__ cw,
                                     int p, int e, int lane, float* acc) {
  int2 q[8];
#pragma unroll
  for (int i = 0; i < 8; ++i) {
    int pi = p + i;
    if (TAIL) pi = (pi < e) ? pi : (e - 1);
    q[i] = cw[pi];
  }
  uint4 v[8];
#pragma unroll
  for (int i = 0; i < 8; ++i)
    v[i] = *reinterpret_cast<const uint4*>(Xb + (size_t)q[i].x * DFEAT + lane * 8);
#pragma unroll
  for (int i = 0; i < 8; ++i) {
    float w = __int_as_float(q[i].y);
    if (TAIL) w = (p + i < e) ? w : 0.0f;
    acc[0] = fmaf(w, bf2f_lo(v[i].x), acc[0]); acc[1] = fmaf(w, bf2f_hi(v[i].x), acc[1]);
    acc[2] = fmaf(w, bf2f_lo(v[i].y), acc[2]); acc[3] = fmaf(w, bf2f_hi(v[i].y), acc[3]);
    acc[4] = fmaf(w, bf2f_lo(v[i].z), acc[4]); acc[5] = fmaf(w, bf2f_hi(v[i].z), acc[5]);
    acc[6] = fmaf(w, bf2f_lo(v[i].w), acc[6]); acc[7] = fmaf(w, bf2f_hi(v[i].w), acc[7]);
  }
}

// One wave per dst row; lane handles features [lane*8, lane*8+8).
// Launched in 4 quarters (~32 µs each) to keep the top-5 visibility window low.
__global__ __launch_bounds__(256) void k_aggregate(const unsigned short* __restrict__ Xb,
                                                   const int2* __restrict__ cw,
                                                   const int* __restrict__ rowStart,
                                                   unsigned short* __restrict__ Y,
                                                   int N, int rowOff) {
  const int row = rowOff + blockIdx.x * 4 + (threadIdx.x >> 6);
  const int lane = threadIdx.x & 63;
  float acc[8] = {0.f, 0.f, 0.f, 0.f, 0.f, 0.f, 0.f, 0.f};
  if (row < N) {
    const int s = rowStart[row], e = rowStart[row + 1];  // e > s always (self-loop)
    int p = s;
    for (; p + 8 <= e; p += 8) agg8<false>(Xb, cw, p, e, lane, acc);
    if (p < e) agg8<true>(Xb, cw, p, e, lane, acc);
    const float sc = rsqrtf((float)(e - s));
#pragma unroll
    for (int j = 0; j < 8; ++j) acc[j] *= sc;
  }
  uint4 o;
  o.x = (unsigned)f2bf(acc[0]) | ((unsigned)f2bf(acc[1]) << 16);
  o.y = (unsigned)f2bf(acc[2]) | ((unsigned)f2bf(acc[3]) << 16);
  o.z = (unsigned)f2bf(acc[4]) | ((unsigned)f2bf(acc[5]) << 16);
  o.w = (unsigned)f2bf(acc[6]) | ((unsigned)f2bf(acc[7]) << 16);
  *reinterpret_cast<uint4*>(Y + (size_t)row * DFEAT + lane * 8) = o;
}

// out[M x 512] = LeakyReLU( Y(bf16) @ W + b ). 128x128 tile, BK=32,
// global_load_lds width-16 staging, 4 waves x (64x64 via 4x4 mfma 16x16x32).
// 1D grid, n-fastest + bijective chunked XCD swizzle (m204 form: nwg%8 != 0).
__global__ __launch_bounds__(256) void k_gemm(const unsigned short* __restrict__ Y,
                                              const unsigned short* __restrict__ Wt,
                                              const float* __restrict__ bias,
                                              float* __restrict__ out, int M) {
  __shared__ unsigned short As[BM * BK];  // 8 KB
  __shared__ unsigned short Bs[BN * BK];  // 8 KB
  const int tid = threadIdx.x;
  const int lane = tid & 63;
  const int wave = tid >> 6;
  const int l16 = lane & 15;
  const int quad = lane >> 4;
  const int wm = (wave >> 1) * 64;
  const int wn = (wave & 1) * 64;

  // bijective chunked XCD swizzle (nwg = Mtiles*4 = 1564, q=195, r=4)
  const int nwg = gridDim.x;
  const int q8 = nwg >> 3, r8 = nwg & 7;
  const int xcd = blockIdx.x & 7, loc = blockIdx.x >> 3;
  const int wg = (xcd < r8 ? xcd * (q8 + 1) : r8 * (q8 + 1) + (xcd - r8) * q8) + loc;
  const int m0 = (wg >> 2) * BM;   // n fastest -> A-panel reuse across 4 consecutive wg
  const int n0 = (wg & 3) * BN;

  f32x4 acc[4][4];
#pragma unroll
  for (int mi = 0; mi < 4; ++mi)
#pragma unroll
    for (int ni = 0; ni < 4; ++ni) { f32x4 z = {0.f, 0.f, 0.f, 0.f}; acc[mi][ni] = z; }

  // staging: LDS slot ci (16B units) holds global chunk (row=ci>>2, kq=((ci&3)-(row>>1))&3)
  const int ci0 = wave * 64 + lane;
  const int ci1 = 256 + ci0;
  const int ra0 = ci0 >> 2, ka0 = (((ci0 & 3) - (ra0 >> 1)) & 3) * 8;
  const int ra1 = ci1 >> 2, ka1 = (((ci1 & 3) - (ra1 >> 1)) & 3) * 8;

  const unsigned short* Ag0 = Y + (size_t)(m0 + ra0) * DFEAT + ka0;
  const unsigned short* Ag1 = Y + (size_t)(m0 + ra1) * DFEAT + ka1;
  const unsigned short* Bg0 = Wt + (size_t)(n0 + ra0) * DFEAT + ka0;
  const unsigned short* Bg1 = Wt + (size_t)(n0 + ra1) * DFEAT + ka1;
  unsigned short* La0 = As + ci0 * 8;
  unsigned short* La1 = As + ci1 * 8;
  unsigned short* Lb0 = Bs + ci0 * 8;
  unsigned short* Lb1 = Bs + ci1 * 8;

  // read side: fragment (row, kq=quad) lives at slot row*4 + ((quad + (row>>1)) & 3)
  const int rotA = (quad + ((wm + l16) >> 1)) & 3;   // same for all mi (16*mi/2 % 4 == 0)
  const int rotB = (quad + ((wn + l16) >> 1)) & 3;
  const unsigned short* AsRd = As + (wm + l16) * BK + rotA * 8;
  const unsigned short* BsRd = Bs + (wn + l16) * BK + rotB * 8;

  for (int kk = 0; kk < DFEAT; kk += BK) {
    gl_lds16(Ag0 + kk, La0);
    gl_lds16(Ag1 + kk, La1);
    gl_lds16(Bg0 + kk, Lb0);
    gl_lds16(Bg1 + kk, Lb1);
    __syncthreads();  // drains vmcnt (global_load_lds) per m97 semantics
    bf16x8 av[4], bv[4];
#pragma unroll
    for (int mi = 0; mi < 4; ++mi)
      av[mi] = *reinterpret_cast<const bf16x8*>(AsRd + mi * 16 * BK);
#pragma unroll
    for (int ni = 0; ni < 4; ++ni)
      bv[ni] = *reinterpret_cast<const bf16x8*>(BsRd + ni * 16 * BK);
#pragma unroll
    for (int mi = 0; mi < 4; ++mi)
#pragma unroll
      for (int ni = 0; ni < 4; ++ni)
        acc[mi][ni] = __builtin_amdgcn_mfma_f32_16x16x32_bf16(av[mi], bv[ni], acc[mi][ni], 0, 0, 0);
    __syncthreads();  // protect LDS before next stage
  }

  float bvals[4];
#pragma unroll
  for (int ni = 0; ni < 4; ++ni) bvals[ni] = bias[n0 + wn + 16 * ni + l16];

  // C/D layout: col = lane&15, row = quad*4 + r
#pragma unroll
  for (int mi = 0; mi < 4; ++mi) {
#pragma unroll
    for (int r = 0; r < 4; ++r) {
      int row = m0 + wm + 16 * mi + quad * 4 + r;
      if (row < M) {
#pragma unroll
        for (int ni = 0; ni < 4; ++ni) {
          float v = acc[mi][ni][r] + bvals[ni];
          v = (v >= 0.f) ? v : 0.01f * v;
          out[(size_t)row * DFEAT + n0 + wn + 16 * ni + l16] = v;
        }
      }
    }
  }
}

extern "C" void kernel_launch(void* const* d_in, const int* in_sizes, int n_in,
                              void* d_out, int out_size, void* d_ws, size_t ws_size,
                              hipStream_t stream) {
  const float* X = (const float*)d_in[0];
  const float* W = (const float*)d_in[1];
  const float* b = (const float*)d_in[2];
  const int* ei  = (const int*)d_in[3];
  const int D = DFEAT;
  const int N = in_sizes[0] / D;   // 50000
  const int E = in_sizes[3] / 2;   // 800000
  const int* src = ei;
  const int* dst = ei + E;
  float* out = (float*)d_out;

  // carve workspace (256B-aligned slices)
  uintptr_t p = (uintptr_t)d_ws;
  auto carve = [&](size_t bytes) -> void* {
    uintptr_t r = p;
    p += (bytes + 255) & ~(size_t)255;
    return (void*)r;
  };
  int*   deg      = (int*)carve(sizeof(int) * (size_t)N);
  int*   rowStart = (int*)carve(sizeof(int) * (size_t)(N + 1));
  int*   fillPos  = (int*)carve(sizeof(int) * (size_t)N);
  int2*  cw       = (int2*)carve(sizeof(int2) * (size_t)(E + N));
  unsigned short* Wt = (unsigned short*)carve(sizeof(unsigned short) * (size_t)D * D);
  const int Mtiles = (N + BM - 1) / BM;     // 391
  const int Mpad = Mtiles * BM;             // 50048
  unsigned short* Y  = (unsigned short*)carve(sizeof(unsigned short) * (size_t)Mpad * D);

  // Xb (bf16 X) lives in d_out: 51.2 MB needed, 102.4 MB available; dead before k_gemm writes.
  unsigned short* Xb = (unsigned short*)d_out;

  const int total8 = N * D / 8;
  const int cb = (E + 255) / 256;
  const int xb = (total8 + 255) / 256;
  const int quarter = ((Mpad / 4 + 3) & ~3);   // 12512, multiple of 4 rows/block

  hipMemsetAsync(deg, 0, sizeof(int) * (size_t)N, stream);
  hipLaunchKernelGGL(k_pre,   dim3(cb + 1024 + xb), dim3(256), 0, stream,
                     dst, deg, E, W, Wt, X, Xb, total8);
  hipLaunchKernelGGL(k_scan,  dim3((N + 1023) / 1024), dim3(1024), 0, stream,
                     deg, rowStart, fillPos, N);
  hipLaunchKernelGGL(k_fill,  dim3((E + N + 255) / 256), dim3(256), 0, stream,
                     src, dst, fillPos, cw, deg, E, N);
  for (int qq = 0; qq < 4; ++qq) {
    const int ro = qq * quarter;
    const int nr = (qq == 3) ? (Mpad - 3 * quarter) : quarter;
    hipLaunchKernelGGL(k_aggregate, dim3(nr / 4), dim3(256), 0, stream,
                       Xb, cw, rowStart, Y, N, ro);
  }
  hipLaunchKernelGGL(k_gemm,  dim3(Mtiles * 4), dim3(256), 0, stream, Y, Wt, b, out, N);
}

// Round 7
// 442.629 us; speedup vs baseline: 1.2065x; 1.0075x over previous
//
#include <hip/hip_runtime.h>
#include <cstdint>
#include <cstddef>

#define DFEAT 512
#define BM 128
#define BN 128
#define BK 32

typedef __attribute__((ext_vector_type(8))) short bf16x8;
typedef __attribute__((ext_vector_type(4))) float f32x4;

#define GLOBAL_AS __attribute__((address_space(1)))
#define LDS_AS __attribute__((address_space(3)))

// float -> bf16 round-to-nearest-even (finite inputs)
__device__ __forceinline__ unsigned short f2bf(float f) {
  unsigned u = __float_as_uint(f);
  u = u + 0x7fffu + ((u >> 16) & 1u);
  return (unsigned short)(u >> 16);
}

__device__ __forceinline__ float bf2f_lo(unsigned u) { return __uint_as_float(u << 16); }
__device__ __forceinline__ float bf2f_hi(unsigned u) { return __uint_as_float(u & 0xffff0000u); }

__device__ __forceinline__ void gl_lds16(const void* g, void* l) {
  __builtin_amdgcn_global_load_lds((const GLOBAL_AS unsigned int*)g,
                                   (LDS_AS unsigned int*)l, 16, 0, 0);
}

// Per-XCD-privatized degree histogram: block b atomics into slice b&7.
// 8x less same-address contention; each 200 KB slice stays in its XCD's L2
// (no cross-XCD line bouncing). Correct for ANY blockIdx->XCD mapping since
// k_reduce sums all slices.
__global__ void k_count(const int* __restrict__ dst, int* __restrict__ deg8,
                        int E, int N) {
  const int i = blockIdx.x * 256 + threadIdx.x;
  if (i < E) {
    const int d = __builtin_nontemporal_load(dst + i);
    atomicAdd(&deg8[(size_t)(blockIdx.x & 7) * N + d], 1);
  }
}

// deg[i] = sum of the 8 privatized slices (8 coalesced streams, 1.6 MB)
__global__ void k_reduce(const int* __restrict__ deg8, int* __restrict__ deg, int N) {
  const int i = blockIdx.x * 256 + threadIdx.x;
  if (i >= N) return;
  int s = 0;
#pragma unroll
  for (int x = 0; x < 8; ++x) s += deg8[(size_t)x * N + i];
  deg[i] = s;
}

// Wt transpose-cast + Xb cast. X loads nontemporal: X is single-use (100 MB)
// and must not evict Xb (51 MB, re-read randomly by k_aggregate) from LLC.
__global__ void k_cast(const float* __restrict__ W, unsigned short* __restrict__ Wt,
                       const float* __restrict__ X, unsigned short* __restrict__ Xb,
                       int total8) {
  int b = blockIdx.x;
  if (b < 1024) {                    // Wt[n][k] = bf16(W[k][n]), coalesced read
    int i = b * 256 + threadIdx.x;
    int k = i >> 9, n = i & 511;
    Wt[(size_t)n * DFEAT + k] = f2bf(W[i]);
    return;
  }
  b -= 1024;                         // Xb = bf16(X), 8 elems/thread
  int i = b * 256 + threadIdx.x;
  if (i >= total8) return;
  const f32x4 a = __builtin_nontemporal_load(reinterpret_cast<const f32x4*>(X + (size_t)i * 8));
  const f32x4 c = __builtin_nontemporal_load(reinterpret_cast<const f32x4*>(X + (size_t)i * 8 + 4));
  uint4 o;
  o.x = (unsigned)f2bf(a[0]) | ((unsigned)f2bf(a[1]) << 16);
  o.y = (unsigned)f2bf(a[2]) | ((unsigned)f2bf(a[3]) << 16);
  o.z = (unsigned)f2bf(c[0]) | ((unsigned)f2bf(c[1]) << 16);
  o.w = (unsigned)f2bf(c[2]) | ((unsigned)f2bf(c[3]) << 16);
  *reinterpret_cast<uint4*>(Xb + (size_t)i * 8) = o;
}

// Multi-block recompute-prefix scan of (deg[i]+1) -> rowStart/fillPos.
// Block b: (1) coalesced sum of deg[0..b*1024) + LDS tree reduce = prefix base;
// (2) 1024-wide Hillis-Steele over its own chunk; (3) write out.
__global__ __launch_bounds__(1024) void k_scan(const int* __restrict__ deg,
                                               int* __restrict__ rowStart,
                                               int* __restrict__ fillPos, int N) {
  const int t = threadIdx.x;
  const int base = blockIdx.x * 1024;
  __shared__ int sm[1024];
  // 1) prefix base = sum_{i<base} (deg[i]+1)
  int pre = 0;
  for (int i = t; i < base; i += 1024) pre += deg[i] + 1;
  sm[t] = pre;
  __syncthreads();
  for (int d = 512; d > 0; d >>= 1) {
    if (t < d) sm[t] += sm[t + d];
    __syncthreads();
  }
  const int blockBase = sm[0];
  __syncthreads();
  // 2) block-local inclusive scan of v = deg[base+t]+1
  const int idx = base + t;
  int v = (idx < N) ? (deg[idx] + 1) : 0;
  sm[t] = v;
  __syncthreads();
  for (int d = 1; d < 1024; d <<= 1) {
    const int o = (t >= d) ? sm[t - d] : 0;
    __syncthreads();
    sm[t] += o;
    __syncthreads();
  }
  if (idx < N) {
    const int ex = blockBase + sm[t] - v;   // exclusive prefix
    rowStart[idx] = ex;
    fillPos[idx] = ex;
    if (idx == N - 1) rowStart[N] = ex + v;
  }
}

// cw[pos] = { src, rsqrt(deg[src]+1) }; pos straight from the fillPos cursor.
__global__ void k_fill(const int* __restrict__ src, const int* __restrict__ dst,
                       int* __restrict__ fillPos, int2* __restrict__ cw,
                       const int* __restrict__ deg, int E, int N) {
  int i = blockIdx.x * blockDim.x + threadIdx.x;
  if (i >= E + N) return;
  int d, s;
  if (i < E) { d = dst[i]; s = src[i]; }
  else       { d = i - E; s = d; }        // self-loop
  int pos = atomicAdd(&fillPos[d], 1);
  int2 q; q.x = s; q.y = __float_as_int(rsqrtf((float)(deg[s] + 1)));
  cw[pos] = q;
}

// 8-deep gather batch: 8 independent cw loads then 8 independent 1KB row
// gathers in flight per wave. TAIL variant clamps the index to e-1 and zeroes
// the weight — duplicate clamped loads are same-address (L1-hit).
template <bool TAIL>
__device__ __forceinline__ void agg8(const unsigned short* __restrict__ Xb,
                                     const int2* __restrict__ cw,
                                     int p, int e, int lane, float* acc) {
  int2 q[8];
#pragma unroll
  for (int i = 0; i < 8; ++i) {
    int pi = p + i;
    if (TAIL) pi = (pi < e) ? pi : (e - 1);
    q[i] = cw[pi];
  }
  uint4 v[8];
#pragma unroll
  for (int i = 0; i < 8; ++i)
    v[i] = *reinterpret_cast<const uint4*>(Xb + (size_t)q[i].x * DFEAT + lane * 8);
#pragma unroll
  for (int i = 0; i < 8; ++i) {
    float w = __int_as_float(q[i].y);
    if (TAIL) w = (p + i < e) ? w : 0.0f;
    acc[0] = fmaf(w, bf2f_lo(v[i].x), acc[0]); acc[1] = fmaf(w, bf2f_hi(v[i].x), acc[1]);
    acc[2] = fmaf(w, bf2f_lo(v[i].y), acc[2]); acc[3] = fmaf(w, bf2f_hi(v[i].y), acc[3]);
    acc[4] = fmaf(w, bf2f_lo(v[i].z), acc[4]); acc[5] = fmaf(w, bf2f_hi(v[i].z), acc[5]);
    acc[6] = fmaf(w, bf2f_lo(v[i].w), acc[6]); acc[7] = fmaf(w, bf2f_hi(v[i].w), acc[7]);
  }
}

// One wave per dst row; lane handles features [lane*8, lane*8+8).
// Launched in 4 quarters (~32 µs each) to keep the top-5 visibility window low.
__global__ __launch_bounds__(256) void k_aggregate(const unsigned short* __restrict__ Xb,
                                                   const int2* __restrict__ cw,
                                                   const int* __restrict__ rowStart,
                                                   unsigned short* __restrict__ Y,
                                                   int N, int rowOff) {
  const int row = rowOff + blockIdx.x * 4 + (threadIdx.x >> 6);
  const int lane = threadIdx.x & 63;
  float acc[8] = {0.f, 0.f, 0.f, 0.f, 0.f, 0.f, 0.f, 0.f};
  if (row < N) {
    const int s = rowStart[row], e = rowStart[row + 1];  // e > s always (self-loop)
    int p = s;
    for (; p + 8 <= e; p += 8) agg8<false>(Xb, cw, p, e, lane, acc);
    if (p < e) agg8<true>(Xb, cw, p, e, lane, acc);
    const float sc = rsqrtf((float)(e - s));
#pragma unroll
    for (int j = 0; j < 8; ++j) acc[j] *= sc;
  }
  uint4 o;
  o.x = (unsigned)f2bf(acc[0]) | ((unsigned)f2bf(acc[1]) << 16);
  o.y = (unsigned)f2bf(acc[2]) | ((unsigned)f2bf(acc[3]) << 16);
  o.z = (unsigned)f2bf(acc[4]) | ((unsigned)f2bf(acc[5]) << 16);
  o.w = (unsigned)f2bf(acc[6]) | ((unsigned)f2bf(acc[7]) << 16);
  *reinterpret_cast<uint4*>(Y + (size_t)row * DFEAT + lane * 8) = o;
}

// out[M x 512] = LeakyReLU( Y(bf16) @ W + b ). 128x128 tile, BK=32,
// global_load_lds width-16 staging, 4 waves x (64x64 via 4x4 mfma 16x16x32).
// 1D grid, n-fastest + bijective chunked XCD swizzle (m204 form: nwg%8 != 0).
__global__ __launch_bounds__(256) void k_gemm(const unsigned short* __restrict__ Y,
                                              const unsigned short* __restrict__ Wt,
                                              const float* __restrict__ bias,
                                              float* __restrict__ out, int M) {
  __shared__ unsigned short As[BM * BK];  // 8 KB
  __shared__ unsigned short Bs[BN * BK];  // 8 KB
  const int tid = threadIdx.x;
  const int lane = tid & 63;
  const int wave = tid >> 6;
  const int l16 = lane & 15;
  const int quad = lane >> 4;
  const int wm = (wave >> 1) * 64;
  const int wn = (wave & 1) * 64;

  // bijective chunked XCD swizzle (nwg = Mtiles*4 = 1564, q=195, r=4)
  const int nwg = gridDim.x;
  const int q8 = nwg >> 3, r8 = nwg & 7;
  const int xcd = blockIdx.x & 7, loc = blockIdx.x >> 3;
  const int wg = (xcd < r8 ? xcd * (q8 + 1) : r8 * (q8 + 1) + (xcd - r8) * q8) + loc;
  const int m0 = (wg >> 2) * BM;   // n fastest -> A-panel reuse across 4 consecutive wg
  const int n0 = (wg & 3) * BN;

  f32x4 acc[4][4];
#pragma unroll
  for (int mi = 0; mi < 4; ++mi)
#pragma unroll
    for (int ni = 0; ni < 4; ++ni) { f32x4 z = {0.f, 0.f, 0.f, 0.f}; acc[mi][ni] = z; }

  // staging: LDS slot ci (16B units) holds global chunk (row=ci>>2, kq=((ci&3)-(row>>1))&3)
  const int ci0 = wave * 64 + lane;
  const int ci1 = 256 + ci0;
  const int ra0 = ci0 >> 2, ka0 = (((ci0 & 3) - (ra0 >> 1)) & 3) * 8;
  const int ra1 = ci1 >> 2, ka1 = (((ci1 & 3) - (ra1 >> 1)) & 3) * 8;

  const unsigned short* Ag0 = Y + (size_t)(m0 + ra0) * DFEAT + ka0;
  const unsigned short* Ag1 = Y + (size_t)(m0 + ra1) * DFEAT + ka1;
  const unsigned short* Bg0 = Wt + (size_t)(n0 + ra0) * DFEAT + ka0;
  const unsigned short* Bg1 = Wt + (size_t)(n0 + ra1) * DFEAT + ka1;
  unsigned short* La0 = As + ci0 * 8;
  unsigned short* La1 = As + ci1 * 8;
  unsigned short* Lb0 = Bs + ci0 * 8;
  unsigned short* Lb1 = Bs + ci1 * 8;

  // read side: fragment (row, kq=quad) lives at slot row*4 + ((quad + (row>>1)) & 3)
  const int rotA = (quad + ((wm + l16) >> 1)) & 3;   // same for all mi (16*mi/2 % 4 == 0)
  const int rotB = (quad + ((wn + l16) >> 1)) & 3;
  const unsigned short* AsRd = As + (wm + l16) * BK + rotA * 8;
  const unsigned short* BsRd = Bs + (wn + l16) * BK + rotB * 8;

  for (int kk = 0; kk < DFEAT; kk += BK) {
    gl_lds16(Ag0 + kk, La0);
    gl_lds16(Ag1 + kk, La1);
    gl_lds16(Bg0 + kk, Lb0);
    gl_lds16(Bg1 + kk, Lb1);
    __syncthreads();  // drains vmcnt (global_load_lds) per m97 semantics
    bf16x8 av[4], bv[4];
#pragma unroll
    for (int mi = 0; mi < 4; ++mi)
      av[mi] = *reinterpret_cast<const bf16x8*>(AsRd + mi * 16 * BK);
#pragma unroll
    for (int ni = 0; ni < 4; ++ni)
      bv[ni] = *reinterpret_cast<const bf16x8*>(BsRd + ni * 16 * BK);
#pragma unroll
    for (int mi = 0; mi < 4; ++mi)
#pragma unroll
      for (int ni = 0; ni < 4; ++ni)
        acc[mi][ni] = __builtin_amdgcn_mfma_f32_16x16x32_bf16(av[mi], bv[ni], acc[mi][ni], 0, 0, 0);
    __syncthreads();  // protect LDS before next stage
  }

  float bvals[4];
#pragma unroll
  for (int ni = 0; ni < 4; ++ni) bvals[ni] = bias[n0 + wn + 16 * ni + l16];

  // C/D layout: col = lane&15, row = quad*4 + r
#pragma unroll
  for (int mi = 0; mi < 4; ++mi) {
#pragma unroll
    for (int r = 0; r < 4; ++r) {
      int row = m0 + wm + 16 * mi + quad * 4 + r;
      if (row < M) {
#pragma unroll
        for (int ni = 0; ni < 4; ++ni) {
          float v = acc[mi][ni][r] + bvals[ni];
          v = (v >= 0.f) ? v : 0.01f * v;
          out[(size_t)row * DFEAT + n0 + wn + 16 * ni + l16] = v;
        }
      }
    }
  }
}

extern "C" void kernel_launch(void* const* d_in, const int* in_sizes, int n_in,
                              void* d_out, int out_size, void* d_ws, size_t ws_size,
                              hipStream_t stream) {
  const float* X = (const float*)d_in[0];
  const float* W = (const float*)d_in[1];
  const float* b = (const float*)d_in[2];
  const int* ei  = (const int*)d_in[3];
  const int D = DFEAT;
  const int N = in_sizes[0] / D;   // 50000
  const int E = in_sizes[3] / 2;   // 800000
  const int* src = ei;
  const int* dst = ei + E;
  float* out = (float*)d_out;

  // carve workspace (256B-aligned slices)
  uintptr_t p = (uintptr_t)d_ws;
  auto carve = [&](size_t bytes) -> void* {
    uintptr_t r = p;
    p += (bytes + 255) & ~(size_t)255;
    return (void*)r;
  };
  int*   deg8     = (int*)carve(sizeof(int) * (size_t)N * 8);
  int*   deg      = (int*)carve(sizeof(int) * (size_t)N);
  int*   rowStart = (int*)carve(sizeof(int) * (size_t)(N + 1));
  int*   fillPos  = (int*)carve(sizeof(int) * (size_t)N);
  int2*  cw       = (int2*)carve(sizeof(int2) * (size_t)(E + N));
  unsigned short* Wt = (unsigned short*)carve(sizeof(unsigned short) * (size_t)D * D);
  const int Mtiles = (N + BM - 1) / BM;     // 391
  const int Mpad = Mtiles * BM;             // 50048
  unsigned short* Y  = (unsigned short*)carve(sizeof(unsigned short) * (size_t)Mpad * D);

  // Xb (bf16 X) lives in d_out: 51.2 MB needed, 102.4 MB available; dead before k_gemm writes.
  unsigned short* Xb = (unsigned short*)d_out;

  const int total8 = N * D / 8;
  const int xb = (total8 + 255) / 256;
  const int quarter = ((Mpad / 4 + 3) & ~3);   // 12512, multiple of 4 rows/block

  hipMemsetAsync(deg8, 0, sizeof(int) * (size_t)N * 8, stream);
  hipLaunchKernelGGL(k_count,  dim3((E + 255) / 256), dim3(256), 0, stream, dst, deg8, E, N);
  hipLaunchKernelGGL(k_reduce, dim3((N + 255) / 256), dim3(256), 0, stream, deg8, deg, N);
  hipLaunchKernelGGL(k_scan,   dim3((N + 1023) / 1024), dim3(1024), 0, stream,
                     deg, rowStart, fillPos, N);
  hipLaunchKernelGGL(k_fill,   dim3((E + N + 255) / 256), dim3(256), 0, stream,
                     src, dst, fillPos, cw, deg, E, N);
  hipLaunchKernelGGL(k_cast,   dim3(1024 + xb), dim3(256), 0, stream, W, Wt, X, Xb, total8);
  for (int qq = 0; qq < 4; ++qq) {
    const int ro = qq * quarter;
    const int nr = (qq == 3) ? (Mpad - 3 * quarter) : quarter;
    hipLaunchKernelGGL(k_aggregate, dim3(nr / 4), dim3(256), 0, stream,
                       Xb, cw, rowStart, Y, N, ro);
  }
  hipLaunchKernelGGL(k_gemm,   dim3(Mtiles * 4), dim3(256), 0, stream, Y, Wt, b, out, N);
}

// Round 8
// 435.020 us; speedup vs baseline: 1.2276x; 1.0175x over previous
//
#include <hip/hip_runtime.h>
#include <cstdint>
#include <cstddef>

#define DFEAT 512
#define BM 128
#define BN 128
#define BK 32

typedef __attribute__((ext_vector_type(8))) short bf16x8;
typedef __attribute__((ext_vector_type(4))) float f32x4;

#define GLOBAL_AS __attribute__((address_space(1)))
#define LDS_AS __attribute__((address_space(3)))

// float -> bf16 round-to-nearest-even (finite inputs)
__device__ __forceinline__ unsigned short f2bf(float f) {
  unsigned u = __float_as_uint(f);
  u = u + 0x7fffu + ((u >> 16) & 1u);
  return (unsigned short)(u >> 16);
}

__device__ __forceinline__ float bf2f_lo(unsigned u) { return __uint_as_float(u << 16); }
__device__ __forceinline__ float bf2f_hi(unsigned u) { return __uint_as_float(u & 0xffff0000u); }

__device__ __forceinline__ void gl_lds16(const void* g, void* l) {
  __builtin_amdgcn_global_load_lds((const GLOBAL_AS unsigned int*)g,
                                   (LDS_AS unsigned int*)l, 16, 0, 0);
}

// Per-XCD-privatized degree histogram: block b atomics into slice b&7.
// deg8 counts EDGES only (self-loop folded arithmetically downstream).
__global__ void k_count(const int* __restrict__ dst, int* __restrict__ deg8,
                        int E, int N) {
  const int i = blockIdx.x * 256 + threadIdx.x;
  if (i < E) {
    const int d = __builtin_nontemporal_load(dst + i);
    atomicAdd(&deg8[(size_t)(blockIdx.x & 7) * N + d], 1);
  }
}

// Multi-block recompute-prefix scan. Reads the 8 privatized slices directly
// (k_reduce folded in), writes deg (edge count, for fill's rsqrt), and
// rowStart/fillPos = exclusive scan of deg (NO +1: cw holds edges only).
__global__ __launch_bounds__(1024) void k_scan(const int* __restrict__ deg8,
                                               int* __restrict__ deg,
                                               int* __restrict__ rowStart,
                                               int* __restrict__ fillPos, int N) {
  const int t = threadIdx.x;
  const int base = blockIdx.x * 1024;
  __shared__ int sm[1024];
  // 1) prefix base = sum_{i<base} deg[i], recomputed from slices (no block dep)
  int pre = 0;
  for (int i = t; i < base; i += 1024) {
    int s = 0;
#pragma unroll
    for (int x = 0; x < 8; ++x) s += deg8[(size_t)x * N + i];
    pre += s;
  }
  sm[t] = pre;
  __syncthreads();
  for (int d = 512; d > 0; d >>= 1) {
    if (t < d) sm[t] += sm[t + d];
    __syncthreads();
  }
  const int blockBase = sm[0];
  __syncthreads();
  // 2) block-local inclusive scan of v = deg[idx]
  const int idx = base + t;
  int v = 0;
  if (idx < N) {
#pragma unroll
    for (int x = 0; x < 8; ++x) v += deg8[(size_t)x * N + idx];
    deg[idx] = v;
  }
  sm[t] = v;
  __syncthreads();
  for (int d = 1; d < 1024; d <<= 1) {
    const int o = (t >= d) ? sm[t - d] : 0;
    __syncthreads();
    sm[t] += o;
    __syncthreads();
  }
  if (idx < N) {
    const int ex = blockBase + sm[t] - v;   // exclusive prefix
    rowStart[idx] = ex;
    fillPos[idx] = ex;
    if (idx == N - 1) rowStart[N] = ex + v;
  }
}

// Merged CSR-fill + Wt transpose-cast + Xb cast (disjoint block ranges).
// fill is atomic/scatter-latency-bound, casts are BW-bound -> concurrent
// execution gives ~max instead of sum. cw[pos] = { src, rsqrt(deg[src]+1) }.
__global__ void k_fillcast(const int* __restrict__ src, const int* __restrict__ dst,
                           int* __restrict__ fillPos, int2* __restrict__ cw,
                           const int* __restrict__ deg, int E,
                           const float* __restrict__ W, unsigned short* __restrict__ Wt,
                           const float* __restrict__ X, unsigned short* __restrict__ Xb,
                           int total8) {
  const int fb = (E + 255) >> 8;
  int b = blockIdx.x;
  if (b < fb) {                      // CSR fill (edges only, no self-loops)
    const int i = b * 256 + threadIdx.x;
    if (i < E) {
      const int d = dst[i], s = src[i];
      const int pos = atomicAdd(&fillPos[d], 1);
      int2 q; q.x = s; q.y = __float_as_int(rsqrtf((float)(deg[s] + 1)));
      cw[pos] = q;
    }
    return;
  }
  b -= fb;
  if (b < 1024) {                    // Wt[n][k] = bf16(W[k][n]), coalesced read
    const int i = b * 256 + threadIdx.x;
    const int k = i >> 9, n = i & 511;
    Wt[(size_t)n * DFEAT + k] = f2bf(W[i]);
    return;
  }
  b -= 1024;                         // Xb = bf16(X), 8 elems/thread; X single-use
  const int i = b * 256 + threadIdx.x;
  if (i >= total8) return;
  const f32x4 a = __builtin_nontemporal_load(reinterpret_cast<const f32x4*>(X + (size_t)i * 8));
  const f32x4 c = __builtin_nontemporal_load(reinterpret_cast<const f32x4*>(X + (size_t)i * 8 + 4));
  uint4 o;
  o.x = (unsigned)f2bf(a[0]) | ((unsigned)f2bf(a[1]) << 16);
  o.y = (unsigned)f2bf(a[2]) | ((unsigned)f2bf(a[3]) << 16);
  o.z = (unsigned)f2bf(c[0]) | ((unsigned)f2bf(c[1]) << 16);
  o.w = (unsigned)f2bf(c[2]) | ((unsigned)f2bf(c[3]) << 16);
  *reinterpret_cast<uint4*>(Xb + (size_t)i * 8) = o;
}

// 8-deep gather batch: 8 independent nontemporal cw loads (cw is single-use;
// keep it from evicting Xb in L2) then 8 independent 1KB row gathers in
// flight. TAIL clamps to e-1 / zero-weight (clamped loads are L1 hits).
template <bool TAIL>
__device__ __forceinline__ void agg8(const unsigned short* __restrict__ Xb,
                                     const int2* __restrict__ cw,
                                     int p, int e, int lane, float* acc) {
  unsigned long long q[8];
#pragma unroll
  for (int i = 0; i < 8; ++i) {
    int pi = p + i;
    if (TAIL) pi = (pi < e) ? pi : (e - 1);
    q[i] = __builtin_nontemporal_load(reinterpret_cast<const unsigned long long*>(cw + pi));
  }
  uint4 v[8];
#pragma unroll
  for (int i = 0; i < 8; ++i)
    v[i] = *reinterpret_cast<const uint4*>(Xb + (size_t)(unsigned)q[i] * DFEAT + lane * 8);
#pragma unroll
  for (int i = 0; i < 8; ++i) {
    float w = __uint_as_float((unsigned)(q[i] >> 32));
    if (TAIL) w = (p + i < e) ? w : 0.0f;
    acc[0] = fmaf(w, bf2f_lo(v[i].x), acc[0]); acc[1] = fmaf(w, bf2f_hi(v[i].x), acc[1]);
    acc[2] = fmaf(w, bf2f_lo(v[i].y), acc[2]); acc[3] = fmaf(w, bf2f_hi(v[i].y), acc[3]);
    acc[4] = fmaf(w, bf2f_lo(v[i].z), acc[4]); acc[5] = fmaf(w, bf2f_hi(v[i].z), acc[5]);
    acc[6] = fmaf(w, bf2f_lo(v[i].w), acc[6]); acc[7] = fmaf(w, bf2f_hi(v[i].w), acc[7]);
  }
}

// One wave per dst row; lane handles features [lane*8, lane*8+8).
// Self-loop folded into the init: acc = sc*X[row] (coalesced read), final
// scale sc = rsqrt(edges+1). Single launch (visibility splitting retired).
__global__ __launch_bounds__(256) void k_aggregate(const unsigned short* __restrict__ Xb,
                                                   const int2* __restrict__ cw,
                                                   const int* __restrict__ rowStart,
                                                   unsigned short* __restrict__ Y, int N) {
  const int row = blockIdx.x * 4 + (threadIdx.x >> 6);
  const int lane = threadIdx.x & 63;
  float acc[8] = {0.f, 0.f, 0.f, 0.f, 0.f, 0.f, 0.f, 0.f};
  if (row < N) {
    const int s = rowStart[row], e = rowStart[row + 1];   // e==s allowed (no edges)
    const float sc = rsqrtf((float)(e - s + 1));          // degree incl. self-loop
    const uint4 v0 = *reinterpret_cast<const uint4*>(Xb + (size_t)row * DFEAT + lane * 8);
    acc[0] = sc * bf2f_lo(v0.x); acc[1] = sc * bf2f_hi(v0.x);
    acc[2] = sc * bf2f_lo(v0.y); acc[3] = sc * bf2f_hi(v0.y);
    acc[4] = sc * bf2f_lo(v0.z); acc[5] = sc * bf2f_hi(v0.z);
    acc[6] = sc * bf2f_lo(v0.w); acc[7] = sc * bf2f_hi(v0.w);
    int p = s;
    for (; p + 8 <= e; p += 8) agg8<false>(Xb, cw, p, e, lane, acc);
    if (p < e) agg8<true>(Xb, cw, p, e, lane, acc);
#pragma unroll
    for (int j = 0; j < 8; ++j) acc[j] *= sc;
  }
  uint4 o;
  o.x = (unsigned)f2bf(acc[0]) | ((unsigned)f2bf(acc[1]) << 16);
  o.y = (unsigned)f2bf(acc[2]) | ((unsigned)f2bf(acc[3]) << 16);
  o.z = (unsigned)f2bf(acc[4]) | ((unsigned)f2bf(acc[5]) << 16);
  o.w = (unsigned)f2bf(acc[6]) | ((unsigned)f2bf(acc[7]) << 16);
  *reinterpret_cast<uint4*>(Y + (size_t)row * DFEAT + lane * 8) = o;
}

// out[M x 512] = LeakyReLU( Y(bf16) @ W + b ). 128x128 tile, BK=32,
// global_load_lds width-16 staging, 4 waves x (64x64 via 4x4 mfma 16x16x32).
// 1D grid, n-fastest + bijective chunked XCD swizzle (m204 form: nwg%8 != 0).
__global__ __launch_bounds__(256) void k_gemm(const unsigned short* __restrict__ Y,
                                              const unsigned short* __restrict__ Wt,
                                              const float* __restrict__ bias,
                                              float* __restrict__ out, int M) {
  __shared__ unsigned short As[BM * BK];  // 8 KB
  __shared__ unsigned short Bs[BN * BK];  // 8 KB
  const int tid = threadIdx.x;
  const int lane = tid & 63;
  const int wave = tid >> 6;
  const int l16 = lane & 15;
  const int quad = lane >> 4;
  const int wm = (wave >> 1) * 64;
  const int wn = (wave & 1) * 64;

  // bijective chunked XCD swizzle (nwg = Mtiles*4 = 1564, q=195, r=4)
  const int nwg = gridDim.x;
  const int q8 = nwg >> 3, r8 = nwg & 7;
  const int xcd = blockIdx.x & 7, loc = blockIdx.x >> 3;
  const int wg = (xcd < r8 ? xcd * (q8 + 1) : r8 * (q8 + 1) + (xcd - r8) * q8) + loc;
  const int m0 = (wg >> 2) * BM;   // n fastest -> A-panel reuse across 4 consecutive wg
  const int n0 = (wg & 3) * BN;

  f32x4 acc[4][4];
#pragma unroll
  for (int mi = 0; mi < 4; ++mi)
#pragma unroll
    for (int ni = 0; ni < 4; ++ni) { f32x4 z = {0.f, 0.f, 0.f, 0.f}; acc[mi][ni] = z; }

  // staging: LDS slot ci (16B units) holds global chunk (row=ci>>2, kq=((ci&3)-(row>>1))&3)
  const int ci0 = wave * 64 + lane;
  const int ci1 = 256 + ci0;
  const int ra0 = ci0 >> 2, ka0 = (((ci0 & 3) - (ra0 >> 1)) & 3) * 8;
  const int ra1 = ci1 >> 2, ka1 = (((ci1 & 3) - (ra1 >> 1)) & 3) * 8;

  const unsigned short* Ag0 = Y + (size_t)(m0 + ra0) * DFEAT + ka0;
  const unsigned short* Ag1 = Y + (size_t)(m0 + ra1) * DFEAT + ka1;
  const unsigned short* Bg0 = Wt + (size_t)(n0 + ra0) * DFEAT + ka0;
  const unsigned short* Bg1 = Wt + (size_t)(n0 + ra1) * DFEAT + ka1;
  unsigned short* La0 = As + ci0 * 8;
  unsigned short* La1 = As + ci1 * 8;
  unsigned short* Lb0 = Bs + ci0 * 8;
  unsigned short* Lb1 = Bs + ci1 * 8;

  // read side: fragment (row, kq=quad) lives at slot row*4 + ((quad + (row>>1)) & 3)
  const int rotA = (quad + ((wm + l16) >> 1)) & 3;   // same for all mi (16*mi/2 % 4 == 0)
  const int rotB = (quad + ((wn + l16) >> 1)) & 3;
  const unsigned short* AsRd = As + (wm + l16) * BK + rotA * 8;
  const unsigned short* BsRd = Bs + (wn + l16) * BK + rotB * 8;

  for (int kk = 0; kk < DFEAT; kk += BK) {
    gl_lds16(Ag0 + kk, La0);
    gl_lds16(Ag1 + kk, La1);
    gl_lds16(Bg0 + kk, Lb0);
    gl_lds16(Bg1 + kk, Lb1);
    __syncthreads();  // drains vmcnt (global_load_lds) per m97 semantics
    bf16x8 av[4], bv[4];
#pragma unroll
    for (int mi = 0; mi < 4; ++mi)
      av[mi] = *reinterpret_cast<const bf16x8*>(AsRd + mi * 16 * BK);
#pragma unroll
    for (int ni = 0; ni < 4; ++ni)
      bv[ni] = *reinterpret_cast<const bf16x8*>(BsRd + ni * 16 * BK);
#pragma unroll
    for (int mi = 0; mi < 4; ++mi)
#pragma unroll
      for (int ni = 0; ni < 4; ++ni)
        acc[mi][ni] = __builtin_amdgcn_mfma_f32_16x16x32_bf16(av[mi], bv[ni], acc[mi][ni], 0, 0, 0);
    __syncthreads();  // protect LDS before next stage
  }

  float bvals[4];
#pragma unroll
  for (int ni = 0; ni < 4; ++ni) bvals[ni] = bias[n0 + wn + 16 * ni + l16];

  // C/D layout: col = lane&15, row = quad*4 + r
#pragma unroll
  for (int mi = 0; mi < 4; ++mi) {
#pragma unroll
    for (int r = 0; r < 4; ++r) {
      int row = m0 + wm + 16 * mi + quad * 4 + r;
      if (row < M) {
#pragma unroll
        for (int ni = 0; ni < 4; ++ni) {
          float v = acc[mi][ni][r] + bvals[ni];
          v = (v >= 0.f) ? v : 0.01f * v;
          out[(size_t)row * DFEAT + n0 + wn + 16 * ni + l16] = v;
        }
      }
    }
  }
}

extern "C" void kernel_launch(void* const* d_in, const int* in_sizes, int n_in,
                              void* d_out, int out_size, void* d_ws, size_t ws_size,
                              hipStream_t stream) {
  const float* X = (const float*)d_in[0];
  const float* W = (const float*)d_in[1];
  const float* b = (const float*)d_in[2];
  const int* ei  = (const int*)d_in[3];
  const int D = DFEAT;
  const int N = in_sizes[0] / D;   // 50000
  const int E = in_sizes[3] / 2;   // 800000
  const int* src = ei;
  const int* dst = ei + E;
  float* out = (float*)d_out;

  // carve workspace (256B-aligned slices)
  uintptr_t p = (uintptr_t)d_ws;
  auto carve = [&](size_t bytes) -> void* {
    uintptr_t r = p;
    p += (bytes + 255) & ~(size_t)255;
    return (void*)r;
  };
  int*   deg8     = (int*)carve(sizeof(int) * (size_t)N * 8);
  int*   deg      = (int*)carve(sizeof(int) * (size_t)N);
  int*   rowStart = (int*)carve(sizeof(int) * (size_t)(N + 1));
  int*   fillPos  = (int*)carve(sizeof(int) * (size_t)N);
  int2*  cw       = (int2*)carve(sizeof(int2) * (size_t)E);
  unsigned short* Wt = (unsigned short*)carve(sizeof(unsigned short) * (size_t)D * D);
  const int Mtiles = (N + BM - 1) / BM;     // 391
  const int Mpad = Mtiles * BM;             // 50048
  unsigned short* Y  = (unsigned short*)carve(sizeof(unsigned short) * (size_t)Mpad * D);

  // Xb (bf16 X) lives in d_out: 51.2 MB needed, 102.4 MB available; dead before k_gemm writes.
  unsigned short* Xb = (unsigned short*)d_out;

  const int total8 = N * D / 8;
  const int fb = (E + 255) / 256;
  const int xb = (total8 + 255) / 256;

  hipMemsetAsync(deg8, 0, sizeof(int) * (size_t)N * 8, stream);
  hipLaunchKernelGGL(k_count,    dim3((E + 255) / 256), dim3(256), 0, stream, dst, deg8, E, N);
  hipLaunchKernelGGL(k_scan,     dim3((N + 1023) / 1024), dim3(1024), 0, stream,
                     deg8, deg, rowStart, fillPos, N);
  hipLaunchKernelGGL(k_fillcast, dim3(fb + 1024 + xb), dim3(256), 0, stream,
                     src, dst, fillPos, cw, deg, E, W, Wt, X, Xb, total8);
  hipLaunchKernelGGL(k_aggregate, dim3(Mpad / 4), dim3(256), 0, stream,
                     Xb, cw, rowStart, Y, N);
  hipLaunchKernelGGL(k_gemm,     dim3(Mtiles * 4), dim3(256), 0, stream, Y, Wt, b, out, N);
}

// Round 9
// 413.490 us; speedup vs baseline: 1.2915x; 1.0521x over previous
//
#include <hip/hip_runtime.h>
#include <cstdint>
#include <cstddef>

#define DFEAT 512
#define BM 128
#define BN 128
#define BK 32

typedef __attribute__((ext_vector_type(8))) short bf16x8;
typedef __attribute__((ext_vector_type(4))) float f32x4;

#define GLOBAL_AS __attribute__((address_space(1)))
#define LDS_AS __attribute__((address_space(3)))

// float -> bf16 round-to-nearest-even (finite inputs)
__device__ __forceinline__ unsigned short f2bf(float f) {
  unsigned u = __float_as_uint(f);
  u = u + 0x7fffu + ((u >> 16) & 1u);
  return (unsigned short)(u >> 16);
}

__device__ __forceinline__ float bf2f_lo(unsigned u) { return __uint_as_float(u << 16); }
__device__ __forceinline__ float bf2f_hi(unsigned u) { return __uint_as_float(u & 0xffff0000u); }

__device__ __forceinline__ void gl_lds16(const void* g, void* l) {
  __builtin_amdgcn_global_load_lds((const GLOBAL_AS unsigned int*)g,
                                   (LDS_AS unsigned int*)l, 16, 0, 0);
}

// count (latency-bound atomics) STRIPED 1:4 with Xb cast (BW-bound) so both
// roles are co-resident (blocks dispatch in blockIdx order; concatenated
// ranges execute as sequential phases -> sum; striping -> max). R6 measured
// the concatenated version at 75 us ~= sum of parts.
__global__ void k_countcast(const int* __restrict__ dst, int* __restrict__ deg8,
                            int E, int N,
                            const float* __restrict__ X, unsigned short* __restrict__ Xb,
                            int total8) {
  const int b = blockIdx.x;
  const int m = b % 5;
  if (m == 4) {                      // count: per-XCD-privatized histogram slice b&7
    const int i = (b / 5) * 256 + threadIdx.x;
    if (i < E) {
      const int d = __builtin_nontemporal_load(dst + i);
      atomicAdd(&deg8[(size_t)(b & 7) * N + d], 1);
    }
    return;
  }
  const int i = ((b / 5) * 4 + m) * 256 + threadIdx.x;   // Xb = bf16(X), 8 elems/thread
  if (i >= total8) return;
  const f32x4 a = __builtin_nontemporal_load(reinterpret_cast<const f32x4*>(X + (size_t)i * 8));
  const f32x4 c = __builtin_nontemporal_load(reinterpret_cast<const f32x4*>(X + (size_t)i * 8 + 4));
  uint4 o;
  o.x = (unsigned)f2bf(a[0]) | ((unsigned)f2bf(a[1]) << 16);
  o.y = (unsigned)f2bf(a[2]) | ((unsigned)f2bf(a[3]) << 16);
  o.z = (unsigned)f2bf(c[0]) | ((unsigned)f2bf(c[1]) << 16);
  o.w = (unsigned)f2bf(c[2]) | ((unsigned)f2bf(c[3]) << 16);
  *reinterpret_cast<uint4*>(Xb + (size_t)i * 8) = o;
}

// Multi-block recompute-prefix scan. Reads the 8 privatized slices directly,
// writes deg (edge count, for fill's rsqrt) and rowStart/fillPos = exclusive
// scan of deg (no +1: cw holds edges only; self-loop folded into k_aggregate).
__global__ __launch_bounds__(1024) void k_scan(const int* __restrict__ deg8,
                                               int* __restrict__ deg,
                                               int* __restrict__ rowStart,
                                               int* __restrict__ fillPos, int N) {
  const int t = threadIdx.x;
  const int base = blockIdx.x * 1024;
  __shared__ int sm[1024];
  // 1) prefix base = sum_{i<base} deg[i], recomputed from slices (no block dep)
  int pre = 0;
  for (int i = t; i < base; i += 1024) {
    int s = 0;
#pragma unroll
    for (int x = 0; x < 8; ++x) s += deg8[(size_t)x * N + i];
    pre += s;
  }
  sm[t] = pre;
  __syncthreads();
  for (int d = 512; d > 0; d >>= 1) {
    if (t < d) sm[t] += sm[t + d];
    __syncthreads();
  }
  const int blockBase = sm[0];
  __syncthreads();
  // 2) block-local inclusive scan of v = deg[idx]
  const int idx = base + t;
  int v = 0;
  if (idx < N) {
#pragma unroll
    for (int x = 0; x < 8; ++x) v += deg8[(size_t)x * N + idx];
    deg[idx] = v;
  }
  sm[t] = v;
  __syncthreads();
  for (int d = 1; d < 1024; d <<= 1) {
    const int o = (t >= d) ? sm[t - d] : 0;
    __syncthreads();
    sm[t] += o;
    __syncthreads();
  }
  if (idx < N) {
    const int ex = blockBase + sm[t] - v;   // exclusive prefix
    rowStart[idx] = ex;
    fillPos[idx] = ex;
    if (idx == N - 1) rowStart[N] = ex + v;
  }
}

// CSR fill (atomic cursor scatter) STRIPED 3:1 with Wt transpose-cast.
// cw[pos] = { src, rsqrt(deg[src]+1) }.
__global__ void k_fillwt(const int* __restrict__ src, const int* __restrict__ dst,
                         int* __restrict__ fillPos, int2* __restrict__ cw,
                         const int* __restrict__ deg, int E,
                         const float* __restrict__ W, unsigned short* __restrict__ Wt) {
  const int b = blockIdx.x;
  const int m = b & 3;
  if (m == 3) {                      // Wt[n][k] = bf16(W[k][n]), coalesced read
    const int i = (b >> 2) * 256 + threadIdx.x;
    if (i < DFEAT * DFEAT) {
      const int k = i >> 9, n = i & 511;
      Wt[(size_t)n * DFEAT + k] = f2bf(W[i]);
    }
    return;
  }
  const int i = ((b >> 2) * 3 + m) * 256 + threadIdx.x;  // fill
  if (i < E) {
    const int d = dst[i], s = src[i];
    const int pos = atomicAdd(&fillPos[d], 1);
    int2 q; q.x = s; q.y = __float_as_int(rsqrtf((float)(deg[s] + 1)));
    cw[pos] = q;
  }
}

// 8-deep gather batch: 8 independent nontemporal cw loads (cw single-use;
// don't evict Xb from L2) then 8 independent 1KB row gathers in flight.
// TAIL clamps to e-1 / zero-weight (clamped loads are L1 hits).
template <bool TAIL>
__device__ __forceinline__ void agg8(const unsigned short* __restrict__ Xb,
                                     const int2* __restrict__ cw,
                                     int p, int e, int lane, float* acc) {
  unsigned long long q[8];
#pragma unroll
  for (int i = 0; i < 8; ++i) {
    int pi = p + i;
    if (TAIL) pi = (pi < e) ? pi : (e - 1);
    q[i] = __builtin_nontemporal_load(reinterpret_cast<const unsigned long long*>(cw + pi));
  }
  uint4 v[8];
#pragma unroll
  for (int i = 0; i < 8; ++i)
    v[i] = *reinterpret_cast<const uint4*>(Xb + (size_t)(unsigned)q[i] * DFEAT + lane * 8);
#pragma unroll
  for (int i = 0; i < 8; ++i) {
    float w = __uint_as_float((unsigned)(q[i] >> 32));
    if (TAIL) w = (p + i < e) ? w : 0.0f;
    acc[0] = fmaf(w, bf2f_lo(v[i].x), acc[0]); acc[1] = fmaf(w, bf2f_hi(v[i].x), acc[1]);
    acc[2] = fmaf(w, bf2f_lo(v[i].y), acc[2]); acc[3] = fmaf(w, bf2f_hi(v[i].y), acc[3]);
    acc[4] = fmaf(w, bf2f_lo(v[i].z), acc[4]); acc[5] = fmaf(w, bf2f_hi(v[i].z), acc[5]);
    acc[6] = fmaf(w, bf2f_lo(v[i].w), acc[6]); acc[7] = fmaf(w, bf2f_hi(v[i].w), acc[7]);
  }
}

// One wave per dst row; lane handles features [lane*8, lane*8+8).
// Self-loop folded into init: acc = sc*X[row] (coalesced), sc = rsqrt(edges+1).
// At the measured LLC random-gather ceiling (~3.8 TB/s, occupancy-invariant).
__global__ __launch_bounds__(256) void k_aggregate(const unsigned short* __restrict__ Xb,
                                                   const int2* __restrict__ cw,
                                                   const int* __restrict__ rowStart,
                                                   unsigned short* __restrict__ Y, int N) {
  const int row = blockIdx.x * 4 + (threadIdx.x >> 6);
  const int lane = threadIdx.x & 63;
  float acc[8] = {0.f, 0.f, 0.f, 0.f, 0.f, 0.f, 0.f, 0.f};
  if (row < N) {
    const int s = rowStart[row], e = rowStart[row + 1];   // e==s allowed (no edges)
    const float sc = rsqrtf((float)(e - s + 1));          // degree incl. self-loop
    const uint4 v0 = *reinterpret_cast<const uint4*>(Xb + (size_t)row * DFEAT + lane * 8);
    acc[0] = sc * bf2f_lo(v0.x); acc[1] = sc * bf2f_hi(v0.x);
    acc[2] = sc * bf2f_lo(v0.y); acc[3] = sc * bf2f_hi(v0.y);
    acc[4] = sc * bf2f_lo(v0.z); acc[5] = sc * bf2f_hi(v0.z);
    acc[6] = sc * bf2f_lo(v0.w); acc[7] = sc * bf2f_hi(v0.w);
    int p = s;
    for (; p + 8 <= e; p += 8) agg8<false>(Xb, cw, p, e, lane, acc);
    if (p < e) agg8<true>(Xb, cw, p, e, lane, acc);
#pragma unroll
    for (int j = 0; j < 8; ++j) acc[j] *= sc;
  }
  uint4 o;
  o.x = (unsigned)f2bf(acc[0]) | ((unsigned)f2bf(acc[1]) << 16);
  o.y = (unsigned)f2bf(acc[2]) | ((unsigned)f2bf(acc[3]) << 16);
  o.z = (unsigned)f2bf(acc[4]) | ((unsigned)f2bf(acc[5]) << 16);
  o.w = (unsigned)f2bf(acc[6]) | ((unsigned)f2bf(acc[7]) << 16);
  *reinterpret_cast<uint4*>(Y + (size_t)row * DFEAT + lane * 8) = o;
}

// out[M x 512] = LeakyReLU( Y(bf16) @ W + b ). 128x128 tile, BK=32,
// global_load_lds width-16 staging, 4 waves x (64x64 via 4x4 mfma 16x16x32).
// 1D grid, n-fastest + bijective chunked XCD swizzle (m204 form: nwg%8 != 0).
__global__ __launch_bounds__(256) void k_gemm(const unsigned short* __restrict__ Y,
                                              const unsigned short* __restrict__ Wt,
                                              const float* __restrict__ bias,
                                              float* __restrict__ out, int M) {
  __shared__ unsigned short As[BM * BK];  // 8 KB
  __shared__ unsigned short Bs[BN * BK];  // 8 KB
  const int tid = threadIdx.x;
  const int lane = tid & 63;
  const int wave = tid >> 6;
  const int l16 = lane & 15;
  const int quad = lane >> 4;
  const int wm = (wave >> 1) * 64;
  const int wn = (wave & 1) * 64;

  // bijective chunked XCD swizzle (nwg = Mtiles*4 = 1564, q=195, r=4)
  const int nwg = gridDim.x;
  const int q8 = nwg >> 3, r8 = nwg & 7;
  const int xcd = blockIdx.x & 7, loc = blockIdx.x >> 3;
  const int wg = (xcd < r8 ? xcd * (q8 + 1) : r8 * (q8 + 1) + (xcd - r8) * q8) + loc;
  const int m0 = (wg >> 2) * BM;   // n fastest -> A-panel reuse across 4 consecutive wg
  const int n0 = (wg & 3) * BN;

  f32x4 acc[4][4];
#pragma unroll
  for (int mi = 0; mi < 4; ++mi)
#pragma unroll
    for (int ni = 0; ni < 4; ++ni) { f32x4 z = {0.f, 0.f, 0.f, 0.f}; acc[mi][ni] = z; }

  // staging: LDS slot ci (16B units) holds global chunk (row=ci>>2, kq=((ci&3)-(row>>1))&3)
  const int ci0 = wave * 64 + lane;
  const int ci1 = 256 + ci0;
  const int ra0 = ci0 >> 2, ka0 = (((ci0 & 3) - (ra0 >> 1)) & 3) * 8;
  const int ra1 = ci1 >> 2, ka1 = (((ci1 & 3) - (ra1 >> 1)) & 3) * 8;

  const unsigned short* Ag0 = Y + (size_t)(m0 + ra0) * DFEAT + ka0;
  const unsigned short* Ag1 = Y + (size_t)(m0 + ra1) * DFEAT + ka1;
  const unsigned short* Bg0 = Wt + (size_t)(n0 + ra0) * DFEAT + ka0;
  const unsigned short* Bg1 = Wt + (size_t)(n0 + ra1) * DFEAT + ka1;
  unsigned short* La0 = As + ci0 * 8;
  unsigned short* La1 = As + ci1 * 8;
  unsigned short* Lb0 = Bs + ci0 * 8;
  unsigned short* Lb1 = Bs + ci1 * 8;

  // read side: fragment (row, kq=quad) lives at slot row*4 + ((quad + (row>>1)) & 3)
  const int rotA = (quad + ((wm + l16) >> 1)) & 3;   // same for all mi (16*mi/2 % 4 == 0)
  const int rotB = (quad + ((wn + l16) >> 1)) & 3;
  const unsigned short* AsRd = As + (wm + l16) * BK + rotA * 8;
  const unsigned short* BsRd = Bs + (wn + l16) * BK + rotB * 8;

  for (int kk = 0; kk < DFEAT; kk += BK) {
    gl_lds16(Ag0 + kk, La0);
    gl_lds16(Ag1 + kk, La1);
    gl_lds16(Bg0 + kk, Lb0);
    gl_lds16(Bg1 + kk, Lb1);
    __syncthreads();  // drains vmcnt (global_load_lds) per m97 semantics
    bf16x8 av[4], bv[4];
#pragma unroll
    for (int mi = 0; mi < 4; ++mi)
      av[mi] = *reinterpret_cast<const bf16x8*>(AsRd + mi * 16 * BK);
#pragma unroll
    for (int ni = 0; ni < 4; ++ni)
      bv[ni] = *reinterpret_cast<const bf16x8*>(BsRd + ni * 16 * BK);
#pragma unroll
    for (int mi = 0; mi < 4; ++mi)
#pragma unroll
      for (int ni = 0; ni < 4; ++ni)
        acc[mi][ni] = __builtin_amdgcn_mfma_f32_16x16x32_bf16(av[mi], bv[ni], acc[mi][ni], 0, 0, 0);
    __syncthreads();  // protect LDS before next stage
  }

  float bvals[4];
#pragma unroll
  for (int ni = 0; ni < 4; ++ni) bvals[ni] = bias[n0 + wn + 16 * ni + l16];

  // C/D layout: col = lane&15, row = quad*4 + r
#pragma unroll
  for (int mi = 0; mi < 4; ++mi) {
#pragma unroll
    for (int r = 0; r < 4; ++r) {
      int row = m0 + wm + 16 * mi + quad * 4 + r;
      if (row < M) {
#pragma unroll
        for (int ni = 0; ni < 4; ++ni) {
          float v = acc[mi][ni][r] + bvals[ni];
          v = (v >= 0.f) ? v : 0.01f * v;
          out[(size_t)row * DFEAT + n0 + wn + 16 * ni + l16] = v;
        }
      }
    }
  }
}

extern "C" void kernel_launch(void* const* d_in, const int* in_sizes, int n_in,
                              void* d_out, int out_size, void* d_ws, size_t ws_size,
                              hipStream_t stream) {
  const float* X = (const float*)d_in[0];
  const float* W = (const float*)d_in[1];
  const float* b = (const float*)d_in[2];
  const int* ei  = (const int*)d_in[3];
  const int D = DFEAT;
  const int N = in_sizes[0] / D;   // 50000
  const int E = in_sizes[3] / 2;   // 800000
  const int* src = ei;
  const int* dst = ei + E;
  float* out = (float*)d_out;

  // carve workspace (256B-aligned slices)
  uintptr_t p = (uintptr_t)d_ws;
  auto carve = [&](size_t bytes) -> void* {
    uintptr_t r = p;
    p += (bytes + 255) & ~(size_t)255;
    return (void*)r;
  };
  int*   deg8     = (int*)carve(sizeof(int) * (size_t)N * 8);
  int*   deg      = (int*)carve(sizeof(int) * (size_t)N);
  int*   rowStart = (int*)carve(sizeof(int) * (size_t)(N + 1));
  int*   fillPos  = (int*)carve(sizeof(int) * (size_t)N);
  int2*  cw       = (int2*)carve(sizeof(int2) * (size_t)E);
  unsigned short* Wt = (unsigned short*)carve(sizeof(unsigned short) * (size_t)D * D);
  const int Mtiles = (N + BM - 1) / BM;     // 391
  const int Mpad = Mtiles * BM;             // 50048
  unsigned short* Y  = (unsigned short*)carve(sizeof(unsigned short) * (size_t)Mpad * D);

  // Xb (bf16 X) lives in d_out: 51.2 MB needed, 102.4 MB available; dead before k_gemm writes.
  unsigned short* Xb = (unsigned short*)d_out;

  const int total8 = N * D / 8;
  const int fb = (E + 255) / 256;           // 3125 count/fill blocks
  const int xb = (total8 + 255) / 256;      // 12500 Xb-cast blocks
  const int wb = (D * D + 255) / 256;       // 1024 Wt blocks

  // striped grids: count:cast = 1:4 (period 5), fill:wt = 3:1 (period 4)
  const int xq = (xb + 3) / 4;
  const int nA = 5 * (fb > xq ? fb : xq);
  const int fq = (fb + 2) / 3;
  const int nB = 4 * (fq > wb ? fq : wb);

  hipMemsetAsync(deg8, 0, sizeof(int) * (size_t)N * 8, stream);
  hipLaunchKernelGGL(k_countcast, dim3(nA), dim3(256), 0, stream,
                     dst, deg8, E, N, X, Xb, total8);
  hipLaunchKernelGGL(k_scan,      dim3((N + 1023) / 1024), dim3(1024), 0, stream,
                     deg8, deg, rowStart, fillPos, N);
  hipLaunchKernelGGL(k_fillwt,    dim3(nB), dim3(256), 0, stream,
                     src, dst, fillPos, cw, deg, E, W, Wt);
  hipLaunchKernelGGL(k_aggregate, dim3(Mpad / 4), dim3(256), 0, stream,
                     Xb, cw, rowStart, Y, N);
  hipLaunchKernelGGL(k_gemm,      dim3(Mtiles * 4), dim3(256), 0, stream, Y, Wt, b, out, N);
}